// Round 13
// baseline (100.003 us; speedup 1.0000x reference)
//
#include <hip/hip_runtime.h>

typedef _Float16 f16x8 __attribute__((ext_vector_type(8)));
typedef unsigned short u16x8 __attribute__((ext_vector_type(8)));
typedef float f32x4 __attribute__((ext_vector_type(4)));

#define NS 1024
#define NQ 1024
#define DD 128
#define NWAY 8
#define SCHUNK 64            // supports per block (4 waves x 16)
#define NSBLK (NS / SCHUNK)  // 16
#define QPER 16              // queries per block -> grid 16 x 64 = 1024

// d_ws layout: part [NSBLK][NQ][NWAY] f32 at offset 0 (512 KB).

__device__ __forceinline__ f16x8 cvt8(const float* __restrict__ p) {
    float4 v0 = *(const float4*)(p);
    float4 v1 = *(const float4*)(p + 4);
    f16x8 s;
    s[0] = (_Float16)v0.x; s[1] = (_Float16)v0.y;
    s[2] = (_Float16)v0.z; s[3] = (_Float16)v0.w;
    s[4] = (_Float16)v1.x; s[5] = (_Float16)v1.y;
    s[6] = (_Float16)v1.z; s[7] = (_Float16)v1.w;
    return s;
}

// Main: 64 supports x 16 queries per block (wave owns 16 supports x 64 h),
// grid 1024. sim(q,s) = relu(|q-s| @ W1^T + b1) @ W2, class-bucketed via
// LDS atomics; b2 dropped (log_softmax shift-invariant).
// Structure = R10 (best, 92.6 µs) with the prep kernel folded into the
// prologue: inline f32->f16 cvt is spill-safe at (256,2) — R4 (VGPR 120)
// and R6 (VGPR 183) both ran inline cvt at (256,2) with WRITE = 256 KB
// exactly; the cvt-driven spills (R3/R5/R7/R12) only occurred under
// tighter launch_bounds caps. Saves one dispatch + gap (~8 µs).
// MFMA: A = W1 fragment, B = diff fragment -> C rows are h, cols are s;
// h-reduction = per-lane fma + 2 cross-quad shuffles.
// MODULO-2 SOFTWARE PIPELINE: MFMAs for query q+1 interleave with the
// epilogue VALU chain of query q.
// launch_bounds MUST stay (256,2): every tighter cap spilled 8-100 MB.
__global__ __launch_bounds__(256, 2) void siamese_main(
    const float* __restrict__ support_x,
    const int* __restrict__ support_y,
    const float* __restrict__ query_x,
    const float* __restrict__ W1,
    const float* __restrict__ b1,
    const float* __restrict__ W2,
    float* __restrict__ part)   // [NSBLK][NQ][NWAY]
{
    __shared__ _Float16 qtile[QPER][DD];       // 4 KB
    __shared__ float clsbuf[QPER][NWAY];       // 512 B

    const int t = threadIdx.x;
    const int wave = t >> 6;
    const int lane = t & 63;
    const int c = lane & 15;     // MFMA n index -> support col
    const int quad = lane >> 4;  // MFMA k-group / C row-group

    const int sblk = blockIdx.x & (NSBLK - 1);
    const int qblk = blockIdx.x >> 4;
    const int s0 = sblk * SCHUNK;
    const int q0 = qblk * QPER;

    // ---- one-time: support B-fragments (inline f32->f16) ----
    // sup[k]: lane (quad,c) holds support row s0+wave*16+c, d=k*32+quad*8+[0,8)
    f16x8 sup[4];
    {
        const float* sp = support_x + (size_t)(s0 + wave * 16 + c) * DD + quad * 8;
#pragma unroll
        for (int k = 0; k < 4; ++k)
            sup[k] = cvt8(sp + k * 32);
    }

    // ---- one-time: W1 A-fragments (inline f32->f16) ----
    // afrag[j][k]: lane (quad,c) holds W1[h=j*16+c][d=k*32+quad*8+[0,8))
    f16x8 afrag[4][4];
#pragma unroll
    for (int j = 0; j < 4; ++j) {
        const float* wp = W1 + (size_t)(j * 16 + c) * DD + quad * 8;
#pragma unroll
        for (int k = 0; k < 4; ++k)
            afrag[j][k] = cvt8(wp + k * 32);
    }

    // ---- one-time: b1/W2 rows for this lane (h = j*16 + quad*4 + r) ----
    f32x4 b1v[4], w2v[4];
#pragma unroll
    for (int j = 0; j < 4; ++j) {
        b1v[j] = *(const f32x4*)(b1 + j * 16 + quad * 4);
        w2v[j] = *(const f32x4*)(W2 + j * 16 + quad * 4);
    }

    const int lbl = support_y[s0 + wave * 16 + c];

    // ---- stage QPER query rows (inline f32->f16) ----
    {
        const int q = t >> 4;
        const int dd = (t & 15) * 8;
        *(f16x8*)&qtile[q][dd] = cvt8(query_x + (size_t)(q0 + q) * DD + dd);
    }
    if (t < QPER * NWAY) clsbuf[t >> 3][t & 7] = 0.f;
    __syncthreads();

    auto read_qf = [&](f16x8 (&qf)[4], int qq) {
#pragma unroll
        for (int k = 0; k < 4; ++k)
            qf[k] = *(const f16x8*)&qtile[qq][k * 32 + quad * 8];
    };
    auto mfma_q = [&](f32x4 (&acc)[4], const f16x8 (&qf)[4]) {
#pragma unroll
        for (int j = 0; j < 4; ++j) acc[j] = b1v[j];
#pragma unroll
        for (int k = 0; k < 4; ++k) {
            union { f16x8 f; u16x8 u; } cv;
            cv.f = sup[k] - qf[k];
            cv.u = cv.u & (unsigned short)0x7fffu;  // |diff|
#pragma unroll
            for (int j = 0; j < 4; ++j)
                acc[j] = __builtin_amdgcn_mfma_f32_16x16x32_f16(
                    afrag[j][k], cv.f, acc[j], 0, 0, 0);
        }
    };
    auto epi = [&](const f32x4 (&acc)[4], int qq) {
        float val = 0.f;
#pragma unroll
        for (int j = 0; j < 4; ++j)
#pragma unroll
            for (int r = 0; r < 4; ++r)
                val = fmaf(fmaxf(acc[j][r], 0.f), w2v[j][r], val);
        val += __shfl_xor(val, 16);
        val += __shfl_xor(val, 32);
        if (quad == 0) atomicAdd(&clsbuf[qq][lbl], val);
    };

    // -------- modulo-2 skewed pipeline over the 16 queries --------
    f16x8 qfA[4], qfB[4];
    f32x4 accA[4], accB[4];
    read_qf(qfA, 0);
    mfma_q(accA, qfA);
    read_qf(qfB, 1);
    for (int qq = 0; qq + 2 < QPER; qq += 2) {
        mfma_q(accB, qfB);      // MFMAs for qq+1 ...
        epi(accA, qq);          // ... interleave with epilogue of qq
        read_qf(qfA, qq + 2);
        mfma_q(accA, qfA);      // MFMAs for qq+2 ...
        epi(accB, qq + 1);      // ... interleave with epilogue of qq+1
        read_qf(qfB, qq + 3);
    }
    mfma_q(accB, qfB);
    epi(accA, QPER - 2);
    epi(accB, QPER - 1);

    __syncthreads();

    // one coalesced 128-float store: part[sblk][q0..q0+15][0..7]
    if (t < QPER * NWAY)
        part[(size_t)sblk * (NQ * NWAY) + q0 * NWAY + t] = clsbuf[t >> 3][t & 7];
}

// Finalize: sum NSBLK partials, counts, per-class mean, log_softmax.
// Grid 8 x 128 threads (one thread per query).
__global__ void siamese_finalize(
    const int* __restrict__ support_y,
    const float* __restrict__ part,
    float* __restrict__ out)
{
    __shared__ float cnt[NWAY];
    const int t = threadIdx.x;
    if (t < NWAY) cnt[t] = 0.f;
    __syncthreads();
#pragma unroll
    for (int i = 0; i < NS / 128; ++i)
        atomicAdd(&cnt[support_y[t * (NS / 128) + i]], 1.0f);
    __syncthreads();

    const int q = blockIdx.x * 128 + t;
    float lg[NWAY];
    float mx = -1e30f;
#pragma unroll
    for (int k = 0; k < NWAY; ++k) {
        float s = 0.f;
#pragma unroll
        for (int sb = 0; sb < NSBLK; ++sb)
            s += part[(size_t)sb * (NQ * NWAY) + q * NWAY + k];
        lg[k] = s / cnt[k];
        mx = fmaxf(mx, lg[k]);
    }
    float ss = 0.f;
#pragma unroll
    for (int k = 0; k < NWAY; ++k) ss += expf(lg[k] - mx);
    const float lse = mx + logf(ss);
#pragma unroll
    for (int k = 0; k < NWAY; ++k) out[q * NWAY + k] = lg[k] - lse;
}

extern "C" void kernel_launch(void* const* d_in, const int* in_sizes, int n_in,
                              void* d_out, int out_size, void* d_ws, size_t ws_size,
                              hipStream_t stream) {
    const float* support_x = (const float*)d_in[0];
    const int* support_y   = (const int*)d_in[1];
    const float* query_x   = (const float*)d_in[2];
    // d_in[3] = n_way (scalar, fixed at 8) — unused
    const float* W1 = (const float*)d_in[4];
    const float* b1 = (const float*)d_in[5];
    const float* W2 = (const float*)d_in[6];
    // d_in[7] = b2 — dropped (uniform logit shift, log_softmax-invariant)

    float* part = (float*)d_ws;   // [NSBLK][NQ][NWAY] f32, 512 KB
    // every slot is written unconditionally by siamese_main — no memset needed

    siamese_main<<<dim3(NSBLK * (NQ / QPER)), dim3(256), 0, stream>>>(
        support_x, support_y, query_x, W1, b1, W2, part);
    siamese_finalize<<<dim3(NQ / 128), dim3(128), 0, stream>>>(
        support_y, part, (float*)d_out);
}

// Round 14
// 95.155 us; speedup vs baseline: 1.0510x; 1.0510x over previous
//
#include <hip/hip_runtime.h>

typedef _Float16 f16x4 __attribute__((ext_vector_type(4)));
typedef _Float16 f16x8 __attribute__((ext_vector_type(8)));
typedef unsigned short u16x8 __attribute__((ext_vector_type(8)));
typedef float f32x4 __attribute__((ext_vector_type(4)));

#define NS 1024
#define NQ 1024
#define DD 128
#define NWAY 8
#define SCHUNK 64            // supports per block (4 waves x 16)
#define NSBLK (NS / SCHUNK)  // 16
#define QPER 32              // queries per block -> grid 512 = 2 blocks/CU

// d_ws layout (bytes):
//   0         part  [NSBLK][NQ][NWAY] f32  (512 KB)
//   0x80000   sup16 [NS][DD] f16           (256 KB)
//   0xC0000   q16   [NQ][DD] f16           (256 KB)
//   0x100000  w1f   [16 frag][64 lane][8] f16 (16 KB, fragment-ordered)

// Prep: one-time f32->f16 conversion of support/query/W1 (W1 directly in
// MFMA fragment order). Keeping conversions out of main removes the
// float4/cvt peak register pressure that drove the R3/R5/R7/R12 spills,
// and halves main's fetch bytes. (R13 proved fusing this back regresses.)
__global__ void siamese_prep(const float* __restrict__ sx,
                             const float* __restrict__ qx,
                             const float* __restrict__ W1,
                             _Float16* __restrict__ sup16,
                             _Float16* __restrict__ q16,
                             _Float16* __restrict__ w1f)
{
    const int tid = blockIdx.x * 256 + threadIdx.x;
    if (blockIdx.x < 128) {                       // support: 32768 float4
        float4 v = ((const float4*)sx)[tid];
        f16x4 h; h[0] = (_Float16)v.x; h[1] = (_Float16)v.y;
        h[2] = (_Float16)v.z; h[3] = (_Float16)v.w;
        ((f16x4*)sup16)[tid] = h;
    } else if (blockIdx.x < 256) {                // query: 32768 float4
        const int i = tid - 32768;
        float4 v = ((const float4*)qx)[i];
        f16x4 h; h[0] = (_Float16)v.x; h[1] = (_Float16)v.y;
        h[2] = (_Float16)v.z; h[3] = (_Float16)v.w;
        ((f16x4*)q16)[i] = h;
    } else {                                      // W1 frags: 16*64 = 1024
        const int i = tid - 65536;
        const int jk = i >> 6, l = i & 63;
        const int h = (jk >> 2) * 16 + (l & 15);
        const int d = (jk & 3) * 32 + (l >> 4) * 8;
        const float* wp = W1 + h * DD + d;
        float4 v0 = *(const float4*)(wp);
        float4 v1 = *(const float4*)(wp + 4);
        f16x8 s;
        s[0] = (_Float16)v0.x; s[1] = (_Float16)v0.y;
        s[2] = (_Float16)v0.z; s[3] = (_Float16)v0.w;
        s[4] = (_Float16)v1.x; s[5] = (_Float16)v1.y;
        s[6] = (_Float16)v1.z; s[7] = (_Float16)v1.w;
        *(f16x8*)(w1f + (size_t)i * 8) = s;
    }
}

// Main: 64 supports x 32 queries per block (wave owns 16 supports x 64 h),
// grid 512 = exactly 2 blocks/CU at (256,2) -> ONE co-resident round
// (R10 ran grid 1024 = two rounds, paying the prologue twice per CU; the
// one-round main structure was validated in R11 — its regression came
// from the SIM-matrix epilogue, not this shape).
// sim(q,s) = relu(|q-s| @ W1^T + b1) @ W2, class-bucketed via LDS
// atomics; b2 dropped (log_softmax shift-invariant).
// MFMA: A = W1 fragment, B = diff fragment -> C rows are h, cols are s;
// h-reduction = per-lane fma + 2 cross-quad shuffles.
// MODULO-2 SOFTWARE PIPELINE: MFMAs for query q+1 interleave with the
// epilogue VALU chain of query q (R10's proven +1.5 µs).
// launch_bounds MUST stay (256,2): every tighter cap (R3/R5/R7/R12)
// spilled 8-100 MB of scratch traffic.
__global__ __launch_bounds__(256, 2) void siamese_main(
    const _Float16* __restrict__ sup16,
    const int* __restrict__ support_y,
    const _Float16* __restrict__ q16,
    const _Float16* __restrict__ w1f,
    const float* __restrict__ b1,
    const float* __restrict__ W2,
    float* __restrict__ part)   // [NSBLK][NQ][NWAY]
{
    __shared__ _Float16 qtile[QPER][DD];       // 8 KB
    __shared__ float clsbuf[QPER][NWAY];       // 1 KB

    const int t = threadIdx.x;
    const int wave = t >> 6;
    const int lane = t & 63;
    const int c = lane & 15;     // MFMA n index -> support col
    const int quad = lane >> 4;  // MFMA k-group / C row-group

    const int sblk = blockIdx.x & (NSBLK - 1);
    const int qblk = blockIdx.x >> 4;
    const int s0 = sblk * SCHUNK;
    const int q0 = qblk * QPER;

    // ---- one-time: support B-fragments (pure f16 16B loads) ----
    // sup[k]: lane (quad,c) holds sup16[s0+wave*16+c][k*32+quad*8 ..+8)
    f16x8 sup[4];
    {
        const _Float16* sp = sup16 + (size_t)(s0 + wave * 16 + c) * DD + quad * 8;
#pragma unroll
        for (int k = 0; k < 4; ++k)
            sup[k] = *(const f16x8*)(sp + k * 32);
    }

    // ---- one-time: W1 A-fragments (fragment-ordered, 16B loads) ----
    f16x8 afrag[4][4];
#pragma unroll
    for (int j = 0; j < 4; ++j)
#pragma unroll
        for (int k = 0; k < 4; ++k)
            afrag[j][k] = *(const f16x8*)(w1f + (size_t)((j * 4 + k) * 64 + lane) * 8);

    // ---- one-time: b1/W2 rows for this lane (h = j*16 + quad*4 + r) ----
    f32x4 b1v[4], w2v[4];
#pragma unroll
    for (int j = 0; j < 4; ++j) {
        b1v[j] = *(const f32x4*)(b1 + j * 16 + quad * 4);
        w2v[j] = *(const f32x4*)(W2 + j * 16 + quad * 4);
    }

    const int lbl = support_y[s0 + wave * 16 + c];

    // ---- stage QPER query rows (f16, 16B copies; 2 chunks/thread) ----
#pragma unroll
    for (int i = 0; i < 2; ++i) {
        const int idx = t + i * 256;
        const int q = idx >> 4;
        const int dd = (idx & 15) * 8;
        *(f16x8*)&qtile[q][dd] = *(const f16x8*)(q16 + (size_t)(q0 + q) * DD + dd);
    }
    clsbuf[t >> 3][t & 7] = 0.f;   // QPER*NWAY == 256: all threads
    __syncthreads();

    auto read_qf = [&](f16x8 (&qf)[4], int qq) {
#pragma unroll
        for (int k = 0; k < 4; ++k)
            qf[k] = *(const f16x8*)&qtile[qq][k * 32 + quad * 8];
    };
    auto mfma_q = [&](f32x4 (&acc)[4], const f16x8 (&qf)[4]) {
#pragma unroll
        for (int j = 0; j < 4; ++j) acc[j] = b1v[j];
#pragma unroll
        for (int k = 0; k < 4; ++k) {
            union { f16x8 f; u16x8 u; } cv;
            cv.f = sup[k] - qf[k];
            cv.u = cv.u & (unsigned short)0x7fffu;  // |diff|
#pragma unroll
            for (int j = 0; j < 4; ++j)
                acc[j] = __builtin_amdgcn_mfma_f32_16x16x32_f16(
                    afrag[j][k], cv.f, acc[j], 0, 0, 0);
        }
    };
    auto epi = [&](const f32x4 (&acc)[4], int qq) {
        float val = 0.f;
#pragma unroll
        for (int j = 0; j < 4; ++j)
#pragma unroll
            for (int r = 0; r < 4; ++r)
                val = fmaf(fmaxf(acc[j][r], 0.f), w2v[j][r], val);
        val += __shfl_xor(val, 16);
        val += __shfl_xor(val, 32);
        if (quad == 0) atomicAdd(&clsbuf[qq][lbl], val);
    };

    // -------- modulo-2 skewed pipeline over the 32 queries --------
    f16x8 qfA[4], qfB[4];
    f32x4 accA[4], accB[4];
    read_qf(qfA, 0);
    mfma_q(accA, qfA);
    read_qf(qfB, 1);
    for (int qq = 0; qq + 2 < QPER; qq += 2) {
        mfma_q(accB, qfB);      // MFMAs for qq+1 ...
        epi(accA, qq);          // ... interleave with epilogue of qq
        read_qf(qfA, qq + 2);
        mfma_q(accA, qfA);      // MFMAs for qq+2 ...
        epi(accB, qq + 1);      // ... interleave with epilogue of qq+1
        read_qf(qfB, qq + 3);
    }
    mfma_q(accB, qfB);
    epi(accA, QPER - 2);
    epi(accB, QPER - 1);

    __syncthreads();

    // one coalesced 256-float store: part[sblk][q0..q0+31][0..7]
    part[(size_t)sblk * (NQ * NWAY) + q0 * NWAY + t] = clsbuf[t >> 3][t & 7];
}

// Finalize: sum NSBLK partials, counts, per-class mean, log_softmax.
// Grid 8 x 128 threads (one thread per query).
__global__ void siamese_finalize(
    const int* __restrict__ support_y,
    const float* __restrict__ part,
    float* __restrict__ out)
{
    __shared__ float cnt[NWAY];
    const int t = threadIdx.x;
    if (t < NWAY) cnt[t] = 0.f;
    __syncthreads();
#pragma unroll
    for (int i = 0; i < NS / 128; ++i)
        atomicAdd(&cnt[support_y[t * (NS / 128) + i]], 1.0f);
    __syncthreads();

    const int q = blockIdx.x * 128 + t;
    float lg[NWAY];
    float mx = -1e30f;
#pragma unroll
    for (int k = 0; k < NWAY; ++k) {
        float s = 0.f;
#pragma unroll
        for (int sb = 0; sb < NSBLK; ++sb)
            s += part[(size_t)sb * (NQ * NWAY) + q * NWAY + k];
        lg[k] = s / cnt[k];
        mx = fmaxf(mx, lg[k]);
    }
    float ss = 0.f;
#pragma unroll
    for (int k = 0; k < NWAY; ++k) ss += expf(lg[k] - mx);
    const float lse = mx + logf(ss);
#pragma unroll
    for (int k = 0; k < NWAY; ++k) out[q * NWAY + k] = lg[k] - lse;
}

extern "C" void kernel_launch(void* const* d_in, const int* in_sizes, int n_in,
                              void* d_out, int out_size, void* d_ws, size_t ws_size,
                              hipStream_t stream) {
    const float* support_x = (const float*)d_in[0];
    const int* support_y   = (const int*)d_in[1];
    const float* query_x   = (const float*)d_in[2];
    // d_in[3] = n_way (scalar, fixed at 8) — unused
    const float* W1 = (const float*)d_in[4];
    const float* b1 = (const float*)d_in[5];
    const float* W2 = (const float*)d_in[6];
    // d_in[7] = b2 — dropped (uniform logit shift, log_softmax-invariant)

    char* ws = (char*)d_ws;
    float* part       = (float*)(ws);                  // 512 KB
    _Float16* sup16   = (_Float16*)(ws + 0x80000);     // 256 KB
    _Float16* q16     = (_Float16*)(ws + 0xC0000);     // 256 KB
    _Float16* w1f     = (_Float16*)(ws + 0x100000);    // 16 KB

    siamese_prep<<<dim3(260), dim3(256), 0, stream>>>(
        support_x, query_x, W1, sup16, q16, w1f);
    siamese_main<<<dim3(NSBLK * (NQ / QPER)), dim3(256), 0, stream>>>(
        sup16, support_y, q16, w1f, b1, W2, part);
    siamese_finalize<<<dim3(NQ / 128), dim3(128), 0, stream>>>(
        support_y, part, (float*)d_out);
}

// Round 15
// 91.679 us; speedup vs baseline: 1.0908x; 1.0379x over previous
//
#include <hip/hip_runtime.h>

typedef _Float16 f16x4 __attribute__((ext_vector_type(4)));
typedef _Float16 f16x8 __attribute__((ext_vector_type(8)));
typedef unsigned short u16x8 __attribute__((ext_vector_type(8)));
typedef float f32x4 __attribute__((ext_vector_type(4)));

#define NS 1024
#define NQ 1024
#define DD 128
#define NWAY 8
#define SCHUNK 64            // supports per block (4 waves x 16)
#define NSBLK (NS / SCHUNK)  // 16
#define QPER 16              // queries per block

// ============================ FINAL (R10) =============================
// Confirmed optimum across 14 structural variants (92.6 µs total):
//  - prep kernel pre-converts inputs to f16 (fusing it back: +7 µs, R13)
//  - main at (256,2): EVERY tighter launch_bounds cap spilled 8-100 MB
//    of scratch traffic (R3/R5/R7/R12)
//  - modulo-2 software pipeline: +1.5 µs over sequential (R10 vs R8)
//  - LDS-atomic class buckets + coalesced partial store (global atomics:
//    catastrophic, R2; SIM materialization: -5 µs, R11)
//  - parallel 8-block finalize (last-block-done fusion: -6.5 µs, R9)
//  - grid 1024 two-round beats one-round QPER=32 (R14: -2.6 µs)
// Remaining time is 40 µs harness d_ws re-poison (~6.7 TB/s, at the
// achievable HBM ceiling) + fixed launch/restore gaps + a latency-bound
// main (~25 µs) that ILP/TLP/pipeline attacks could not move further.
// ======================================================================

// d_ws layout (bytes):
//   0         part  [NSBLK][NQ][NWAY] f32  (512 KB)
//   0x80000   sup16 [NS][DD] f16           (256 KB)
//   0xC0000   q16   [NQ][DD] f16           (256 KB)
//   0x100000  w1f   [16 frag][64 lane][8] f16 (16 KB, fragment-ordered)

__global__ void siamese_prep(const float* __restrict__ sx,
                             const float* __restrict__ qx,
                             const float* __restrict__ W1,
                             _Float16* __restrict__ sup16,
                             _Float16* __restrict__ q16,
                             _Float16* __restrict__ w1f)
{
    const int tid = blockIdx.x * 256 + threadIdx.x;
    if (blockIdx.x < 128) {                       // support: 32768 float4
        float4 v = ((const float4*)sx)[tid];
        f16x4 h; h[0] = (_Float16)v.x; h[1] = (_Float16)v.y;
        h[2] = (_Float16)v.z; h[3] = (_Float16)v.w;
        ((f16x4*)sup16)[tid] = h;
    } else if (blockIdx.x < 256) {                // query: 32768 float4
        const int i = tid - 32768;
        float4 v = ((const float4*)qx)[i];
        f16x4 h; h[0] = (_Float16)v.x; h[1] = (_Float16)v.y;
        h[2] = (_Float16)v.z; h[3] = (_Float16)v.w;
        ((f16x4*)q16)[i] = h;
    } else {                                      // W1 frags: 16*64 = 1024
        const int i = tid - 65536;
        const int jk = i >> 6, l = i & 63;
        const int h = (jk >> 2) * 16 + (l & 15);
        const int d = (jk & 3) * 32 + (l >> 4) * 8;
        const float* wp = W1 + h * DD + d;
        float4 v0 = *(const float4*)(wp);
        float4 v1 = *(const float4*)(wp + 4);
        f16x8 s;
        s[0] = (_Float16)v0.x; s[1] = (_Float16)v0.y;
        s[2] = (_Float16)v0.z; s[3] = (_Float16)v0.w;
        s[4] = (_Float16)v1.x; s[5] = (_Float16)v1.y;
        s[6] = (_Float16)v1.z; s[7] = (_Float16)v1.w;
        *(f16x8*)(w1f + (size_t)i * 8) = s;
    }
}

// Main: 64 supports x 16 queries per block (wave owns 16 supports x 64 h),
// grid 1024. sim(q,s) = relu(|q-s| @ W1^T + b1) @ W2, class-bucketed via
// LDS atomics; b2 dropped (log_softmax shift-invariant).
// MFMA: A = W1 fragment, B = diff fragment -> C rows are h, cols are s;
// h-reduction = per-lane fma + 2 cross-quad shuffles.
__global__ __launch_bounds__(256, 2) void siamese_main(
    const _Float16* __restrict__ sup16,
    const int* __restrict__ support_y,
    const _Float16* __restrict__ q16,
    const _Float16* __restrict__ w1f,
    const float* __restrict__ b1,
    const float* __restrict__ W2,
    float* __restrict__ part)   // [NSBLK][NQ][NWAY]
{
    __shared__ _Float16 qtile[QPER][DD];       // 4 KB
    __shared__ float clsbuf[QPER][NWAY];       // 512 B

    const int t = threadIdx.x;
    const int wave = t >> 6;
    const int lane = t & 63;
    const int c = lane & 15;     // MFMA n index -> support col
    const int quad = lane >> 4;  // MFMA k-group / C row-group

    const int sblk = blockIdx.x & (NSBLK - 1);
    const int qblk = blockIdx.x >> 4;
    const int s0 = sblk * SCHUNK;
    const int q0 = qblk * QPER;

    // ---- one-time: support B-fragments (pure f16 16B loads) ----
    f16x8 sup[4];
    {
        const _Float16* sp = sup16 + (size_t)(s0 + wave * 16 + c) * DD + quad * 8;
#pragma unroll
        for (int k = 0; k < 4; ++k)
            sup[k] = *(const f16x8*)(sp + k * 32);
    }

    // ---- one-time: W1 A-fragments (fragment-ordered, 16B loads) ----
    f16x8 afrag[4][4];
#pragma unroll
    for (int j = 0; j < 4; ++j)
#pragma unroll
        for (int k = 0; k < 4; ++k)
            afrag[j][k] = *(const f16x8*)(w1f + (size_t)((j * 4 + k) * 64 + lane) * 8);

    // ---- one-time: b1/W2 rows for this lane (h = j*16 + quad*4 + r) ----
    f32x4 b1v[4], w2v[4];
#pragma unroll
    for (int j = 0; j < 4; ++j) {
        b1v[j] = *(const f32x4*)(b1 + j * 16 + quad * 4);
        w2v[j] = *(const f32x4*)(W2 + j * 16 + quad * 4);
    }

    const int lbl = support_y[s0 + wave * 16 + c];

    // ---- stage QPER query rows (f16, direct 16B copies) ----
    {
        const int q = t >> 4;
        const int dd = (t & 15) * 8;
        *(f16x8*)&qtile[q][dd] = *(const f16x8*)(q16 + (size_t)(q0 + q) * DD + dd);
    }
    if (t < QPER * NWAY) clsbuf[t >> 3][t & 7] = 0.f;
    __syncthreads();

    auto read_qf = [&](f16x8 (&qf)[4], int qq) {
#pragma unroll
        for (int k = 0; k < 4; ++k)
            qf[k] = *(const f16x8*)&qtile[qq][k * 32 + quad * 8];
    };
    auto mfma_q = [&](f32x4 (&acc)[4], const f16x8 (&qf)[4]) {
#pragma unroll
        for (int j = 0; j < 4; ++j) acc[j] = b1v[j];
#pragma unroll
        for (int k = 0; k < 4; ++k) {
            union { f16x8 f; u16x8 u; } cv;
            cv.f = sup[k] - qf[k];
            cv.u = cv.u & (unsigned short)0x7fffu;  // |diff|
#pragma unroll
            for (int j = 0; j < 4; ++j)
                acc[j] = __builtin_amdgcn_mfma_f32_16x16x32_f16(
                    afrag[j][k], cv.f, acc[j], 0, 0, 0);
        }
    };
    auto epi = [&](const f32x4 (&acc)[4], int qq) {
        float val = 0.f;
#pragma unroll
        for (int j = 0; j < 4; ++j)
#pragma unroll
            for (int r = 0; r < 4; ++r)
                val = fmaf(fmaxf(acc[j][r], 0.f), w2v[j][r], val);
        val += __shfl_xor(val, 16);
        val += __shfl_xor(val, 32);
        if (quad == 0) atomicAdd(&clsbuf[qq][lbl], val);
    };

    // -------- modulo-2 skewed pipeline over the 16 queries --------
    f16x8 qfA[4], qfB[4];
    f32x4 accA[4], accB[4];
    read_qf(qfA, 0);
    mfma_q(accA, qfA);
    read_qf(qfB, 1);
    for (int qq = 0; qq + 2 < QPER; qq += 2) {
        mfma_q(accB, qfB);      // MFMAs for qq+1 ...
        epi(accA, qq);          // ... interleave with epilogue of qq
        read_qf(qfA, qq + 2);
        mfma_q(accA, qfA);      // MFMAs for qq+2 ...
        epi(accB, qq + 1);      // ... interleave with epilogue of qq+1
        read_qf(qfB, qq + 3);
    }
    mfma_q(accB, qfB);
    epi(accA, QPER - 2);
    epi(accB, QPER - 1);

    __syncthreads();

    // one coalesced 128-float store: part[sblk][q0..q0+15][0..7]
    if (t < QPER * NWAY)
        part[(size_t)sblk * (NQ * NWAY) + q0 * NWAY + t] = clsbuf[t >> 3][t & 7];
}

// Finalize: sum NSBLK partials, counts, per-class mean, log_softmax.
// Grid 8 x 128 threads (one thread per query).
__global__ void siamese_finalize(
    const int* __restrict__ support_y,
    const float* __restrict__ part,
    float* __restrict__ out)
{
    __shared__ float cnt[NWAY];
    const int t = threadIdx.x;
    if (t < NWAY) cnt[t] = 0.f;
    __syncthreads();
#pragma unroll
    for (int i = 0; i < NS / 128; ++i)
        atomicAdd(&cnt[support_y[t * (NS / 128) + i]], 1.0f);
    __syncthreads();

    const int q = blockIdx.x * 128 + t;
    float lg[NWAY];
    float mx = -1e30f;
#pragma unroll
    for (int k = 0; k < NWAY; ++k) {
        float s = 0.f;
#pragma unroll
        for (int sb = 0; sb < NSBLK; ++sb)
            s += part[(size_t)sb * (NQ * NWAY) + q * NWAY + k];
        lg[k] = s / cnt[k];
        mx = fmaxf(mx, lg[k]);
    }
    float ss = 0.f;
#pragma unroll
    for (int k = 0; k < NWAY; ++k) ss += expf(lg[k] - mx);
    const float lse = mx + logf(ss);
#pragma unroll
    for (int k = 0; k < NWAY; ++k) out[q * NWAY + k] = lg[k] - lse;
}

extern "C" void kernel_launch(void* const* d_in, const int* in_sizes, int n_in,
                              void* d_out, int out_size, void* d_ws, size_t ws_size,
                              hipStream_t stream) {
    const float* support_x = (const float*)d_in[0];
    const int* support_y   = (const int*)d_in[1];
    const float* query_x   = (const float*)d_in[2];
    // d_in[3] = n_way (scalar, fixed at 8) — unused
    const float* W1 = (const float*)d_in[4];
    const float* b1 = (const float*)d_in[5];
    const float* W2 = (const float*)d_in[6];
    // d_in[7] = b2 — dropped (uniform logit shift, log_softmax-invariant)

    char* ws = (char*)d_ws;
    float* part       = (float*)(ws);                  // 512 KB
    _Float16* sup16   = (_Float16*)(ws + 0x80000);     // 256 KB
    _Float16* q16     = (_Float16*)(ws + 0xC0000);     // 256 KB
    _Float16* w1f     = (_Float16*)(ws + 0x100000);    // 16 KB

    siamese_prep<<<dim3(260), dim3(256), 0, stream>>>(
        support_x, query_x, W1, sup16, q16, w1f);
    siamese_main<<<dim3(NSBLK * (NQ / QPER)), dim3(256), 0, stream>>>(
        sup16, support_y, q16, w1f, b1, W2, part);
    siamese_finalize<<<dim3(NQ / 128), dim3(128), 0, stream>>>(
        support_y, part, (float*)d_out);
}